// Round 10
// baseline (3203.359 us; speedup 1.0000x reference)
//
#include <hip/hip_runtime.h>
#include <hip/hip_bf16.h>

// LinearAttention: B=4, T=8192, E=1024, H=16, D=64
//
// R9: GEMM LDS single-buffered (64KB) -> 2 blocks/CU. Legal because the
// fragment-group split means each region's LDS reads finish one phase
// before its restage (ph4 consumes B01/B23 from REGISTERS). Ledger:
//   stage(t+1): B01@ph2 (+A03@ph2 MODE1), B23@ph3, A47@ph4 (MODE1);
//   MODE0 A via wrA(t+1)@ph3/ph4-post + ldgA(t+2) (4-phase reg prefetch).
//   waits: ph4-end vmcnt(16/0) MODE0, vmcnt(2) MODE1 (guards t+1 B-stages);
//          ph2-end vmcnt(4/0) MODE1 (guards A47(t)); A03/A47 MODE0 via
//          ds_write + >=2-barrier separation.
// MODE0 epilogue: C-bounce in 2x64KB chunks. __launch_bounds__(512,4) pins
// VGPR<=128 so 2 blocks fit. kv/attn/casts byte-identical to R8.

#define SCALE_ 0.125f
#define EPS_FM_ 1e-6f
#define EPS_Z_ 1e-8f

typedef __bf16 bf16;
typedef __attribute__((ext_vector_type(4))) __bf16 bf16x4;
typedef __attribute__((ext_vector_type(8))) __bf16 bf16x8;
typedef __attribute__((ext_vector_type(8))) unsigned short u16x8;
typedef __attribute__((ext_vector_type(4))) float f32x4;

__device__ __forceinline__ void gl_lds16(const void* g, void* l) {
  __builtin_amdgcn_global_load_lds(
      (const __attribute__((address_space(1))) void*)g,
      (__attribute__((address_space(3))) void*)l, 16, 0, 0);
}

#define SBAR()                                  \
  do {                                          \
    __builtin_amdgcn_sched_barrier(0);          \
    asm volatile("s_barrier" ::: "memory");     \
    __builtin_amdgcn_sched_barrier(0);          \
  } while (0)

// ---- weights fp32 -> bf16 (4 matrices, one dispatch)
__global__ __launch_bounds__(256) void cast_weights(
    const float* __restrict__ Wq, const float* __restrict__ Wk,
    const float* __restrict__ Wv, const float* __restrict__ Wo,
    bf16* __restrict__ out) {
  int which = blockIdx.y;
  int j = (blockIdx.x * 256 + threadIdx.x) * 4;
  const float* s = (which == 0) ? Wq : (which == 1) ? Wk : (which == 2) ? Wv : Wo;
  float4 v = *(const float4*)(s + j);
  bf16x4 p = {(bf16)v.x, (bf16)v.y, (bf16)v.z, (bf16)v.w};
  *(bf16x4*)(out + (size_t)which * (1u << 20) + j) = p;
}

// ---- 256^2 8-phase GEMM, single-buffered LDS (64KB), 2 blocks/CU.
// MODE 0: fused 3-projection pass (A fp32, fused cast), grid 1536.
// MODE 1: output GEMM (A bf16 gl_lds, fp32 out), grid 512.
template <int MODE>
__global__ __launch_bounds__(512, 4) void gemm8p(
    const bf16* __restrict__ Ab, const float* __restrict__ Aq,
    const float* __restrict__ Ak, const float* __restrict__ Av,
    const bf16* __restrict__ Wb, const float* __restrict__ b0,
    const float* __restrict__ b1, const float* __restrict__ b2,
    bf16* __restrict__ Pb, float* __restrict__ Pf) {
  __shared__ __align__(16) char lds[65536];
  const int tid = threadIdx.x;
  const int bid = blockIdx.x;
  const int wg = (bid & 7) * (gridDim.x >> 3) + (bid >> 3);
  const int mt = wg >> 2;
  int seg = 0, om = 2;
  if constexpr (MODE == 0) {
    seg = mt >> 7;
    om = (seg < 2) ? 0 : 1;
  }
  const int m0 = (MODE == 0 ? (mt & 127) : mt) * 256;
  const int n0 = (wg & 3) * 256;
  const int wave = tid >> 6, lane = tid & 63;
  const int wm = wave >> 2, wn = wave & 3;
  const int l16 = lane & 15, kg = lane >> 4;
  const int e = l16 & 7;
  const int sw0 = (kg ^ e) << 4;
  const int sw1 = ((4 | kg) ^ e) << 4;

  const int tr = tid >> 3;
  const int cslot = (tid & 7) ^ (tr & 7);
  const bf16* pA = nullptr;
  const float* pAf = nullptr;
  if constexpr (MODE == 1)
    pA = Ab + (size_t)(m0 + tr) * 1024 + cslot * 8;
  else {
    const float* Af = (seg == 0) ? Aq : (seg == 1) ? Ak : Av;
    pAf = Af + (size_t)(m0 + tr) * 1024 + cslot * 8;
  }
  const bf16* W = (MODE == 0) ? Wb + ((size_t)seg << 20) : Wb;
  const float* bias = (MODE == 0) ? ((seg == 0) ? b0 : (seg == 1) ? b1 : b2) : b0;
  const bf16* pB = W + (size_t)(n0 + ((tr >> 5) << 6) + (tr & 31)) * 1024 + cslot * 8;
  char* sA = lds;            // A03 region [0,16K), A47 [16K,32K)
  char* sB = lds + 32768;    // B01 [32K,48K), B23 [48K,64K)

  auto stgA = [&](int h, int kt) {  // MODE1
    const bf16* g = pA + h * 65536 + kt * 64;
    char* d = sA + h * 16384 + tid * 16;
    gl_lds16(g, d);
    gl_lds16(g + 131072, d + 8192);
  };
  auto stgB = [&](int h, int kt) {
    const bf16* g = pB + h * 32768 + kt * 64;
    char* d = sB + h * 16384 + tid * 16;
    gl_lds16(g, d);
    gl_lds16(g + 131072, d + 8192);
  };
  // MODE0: reg-staged fused cast
  auto ldgA = [&](int h, int kt, f32x4* r) {
    const float* g = pAf + h * 65536 + kt * 64;
    r[0] = *(const f32x4*)g;
    r[1] = *(const f32x4*)(g + 4);
    r[2] = *(const f32x4*)(g + 131072);
    r[3] = *(const f32x4*)(g + 131072 + 4);
  };
  auto wrA = [&](int h, const f32x4* r) {
    bf16x8 p0 = {(bf16)r[0][0], (bf16)r[0][1], (bf16)r[0][2], (bf16)r[0][3],
                 (bf16)r[1][0], (bf16)r[1][1], (bf16)r[1][2], (bf16)r[1][3]};
    bf16x8 p1 = {(bf16)r[2][0], (bf16)r[2][1], (bf16)r[2][2], (bf16)r[2][3],
                 (bf16)r[3][0], (bf16)r[3][1], (bf16)r[3][2], (bf16)r[3][3]};
    char* d = sA + h * 16384 + tid * 16;
    *(bf16x8*)d = p0;
    *(bf16x8*)(d + 8192) = p1;
  };

  const int aBase = wm * 8192 + l16 * 128;
  const int bBase = wn * 4096 + l16 * 128;
  auto ldA = [&](int h, int fmi, int kk) {
    return *(const bf16x8*)(sA + h * 16384 + aBase + fmi * 2048 +
                            (kk ? sw1 : sw0));
  };
  auto ldB = [&](int h, int fnj, int kk) {
    return *(const bf16x8*)(sB + h * 16384 + bBase + fnj * 2048 +
                            (kk ? sw1 : sw0));
  };

  f32x4 acc[8][4] = {};
  bf16x8 rA[4][2], rB01[2][2], rB23[2][2];
  f32x4 ga[4], gb[4];
  const int NT = 16;

  if constexpr (MODE == 1) {
    // prologue: tile 0 all regions; A47 guarded later by t0.ph2-end vmcnt(4)
    stgA(0, 0); stgB(0, 0); stgB(1, 0); stgA(1, 0);
    asm volatile("s_waitcnt vmcnt(2)" ::: "memory");
  } else {
    ldgA(0, 0, ga); ldgA(1, 0, gb);
    stgB(0, 0); stgB(1, 0);
    asm volatile("s_waitcnt vmcnt(12)" ::: "memory");
    wrA(0, ga);
    asm volatile("s_waitcnt vmcnt(4)" ::: "memory");
    wrA(1, gb);
    ldgA(0, 1, ga); ldgA(1, 1, gb);
    asm volatile("s_waitcnt vmcnt(16)" ::: "memory");  // B01(0),B23(0) landed
    asm volatile("s_waitcnt lgkmcnt(0)" ::: "memory");
  }
  SBAR();

#pragma unroll 2
  for (int t = 0; t < NT; ++t) {
    // ---- ph1: read A03+B01 (no stages)
#pragma unroll
    for (int fmi = 0; fmi < 4; ++fmi) {
      rA[fmi][0] = ldA(0, fmi, 0);
      rA[fmi][1] = ldA(0, fmi, 1);
    }
#pragma unroll
    for (int fnj = 0; fnj < 2; ++fnj) {
      rB01[fnj][0] = ldB(0, fnj, 0);
      rB01[fnj][1] = ldB(0, fnj, 1);
    }
    SBAR();
    __builtin_amdgcn_s_setprio(1);
#pragma unroll
    for (int fmi = 0; fmi < 4; ++fmi)
#pragma unroll
      for (int fnj = 0; fnj < 2; ++fnj)
#pragma unroll
        for (int kk = 0; kk < 2; ++kk)
          acc[fmi][fnj] = __builtin_amdgcn_mfma_f32_16x16x32_bf16(
              rA[fmi][kk], rB01[fnj][kk], acc[fmi][fnj], 0, 0, 0);
    __builtin_amdgcn_s_setprio(0);
    SBAR();
    // ---- ph2: read B23; stage B01(t+1) (+A03(t+1) MODE1)
#pragma unroll
    for (int fnj = 0; fnj < 2; ++fnj) {
      rB23[fnj][0] = ldB(1, fnj, 0);
      rB23[fnj][1] = ldB(1, fnj, 1);
    }
    if (t + 1 < NT) {
      if constexpr (MODE == 1) stgA(0, t + 1);
      stgB(0, t + 1);
    }
    SBAR();
    __builtin_amdgcn_s_setprio(1);
#pragma unroll
    for (int fmi = 0; fmi < 4; ++fmi)
#pragma unroll
      for (int fnj = 0; fnj < 2; ++fnj)
#pragma unroll
        for (int kk = 0; kk < 2; ++kk)
          acc[fmi][2 + fnj] = __builtin_amdgcn_mfma_f32_16x16x32_bf16(
              rA[fmi][kk], rB23[fnj][kk], acc[fmi][2 + fnj], 0, 0, 0);
    __builtin_amdgcn_s_setprio(0);
    __builtin_amdgcn_sched_barrier(0);
    if constexpr (MODE == 1) {  // guard A47(t) (staged (t-1).ph4) before ph3 reads
      if (t + 1 < NT)
        asm volatile("s_waitcnt vmcnt(4)" ::: "memory");
      else
        asm volatile("s_waitcnt vmcnt(0)" ::: "memory");
    }
    SBAR();
    // ---- ph3: read A47; stage B23(t+1); MODE0 post: wrA03(t+1)+ldgA03(t+2)
#pragma unroll
    for (int fmi = 0; fmi < 4; ++fmi) {
      rA[fmi][0] = ldA(1, fmi, 0);
      rA[fmi][1] = ldA(1, fmi, 1);
    }
    if (t + 1 < NT) stgB(1, t + 1);
    SBAR();
    __builtin_amdgcn_s_setprio(1);
#pragma unroll
    for (int fmi = 0; fmi < 4; ++fmi)
#pragma unroll
      for (int fnj = 0; fnj < 2; ++fnj)
#pragma unroll
        for (int kk = 0; kk < 2; ++kk)
          acc[4 + fmi][2 + fnj] = __builtin_amdgcn_mfma_f32_16x16x32_bf16(
              rA[fmi][kk], rB23[fnj][kk], acc[4 + fmi][2 + fnj], 0, 0, 0);
    __builtin_amdgcn_s_setprio(0);
    __builtin_amdgcn_sched_barrier(0);
    if constexpr (MODE == 0) {
      if (t + 1 < NT) {
        wrA(0, ga);
        if (t + 2 < NT) ldgA(0, t + 2, ga);
      }
    }
    SBAR();
    // ---- ph4: MODE1 stage A47(t+1); MFMA A47xB01(regs); MODE0 post:
    //           wrA47(t+1)+ldgA47(t+2); tile-boundary vmcnt; SBAR
    if constexpr (MODE == 1) {
      if (t + 1 < NT) stgA(1, t + 1);
    }
    SBAR();
    __builtin_amdgcn_s_setprio(1);
#pragma unroll
    for (int fmi = 0; fmi < 4; ++fmi)
#pragma unroll
      for (int fnj = 0; fnj < 2; ++fnj)
#pragma unroll
        for (int kk = 0; kk < 2; ++kk)
          acc[4 + fmi][fnj] = __builtin_amdgcn_mfma_f32_16x16x32_bf16(
              rA[fmi][kk], rB01[fnj][kk], acc[4 + fmi][fnj], 0, 0, 0);
    __builtin_amdgcn_s_setprio(0);
    __builtin_amdgcn_sched_barrier(0);
    if constexpr (MODE == 0) {
      if (t + 1 < NT) {
        wrA(1, gb);
        if (t + 2 < NT) ldgA(1, t + 2, gb);
        if (t + 2 < NT)
          asm volatile("s_waitcnt vmcnt(16)" ::: "memory");
        else
          asm volatile("s_waitcnt vmcnt(0)" ::: "memory");
      }
    } else {
      if (t + 1 < NT)
        asm volatile("s_waitcnt vmcnt(2)" ::: "memory");
    }
    SBAR();
  }

  // ---- epilogue
  if constexpr (MODE == 0) {
    // C-bounce in 2 chunks of 64KB (rows wm*128..): coalesced 512B stores.
    bf16* PbS = Pb + (size_t)seg * 33554432u;
#pragma unroll
    for (int hk = 0; hk < 2; ++hk) {
      if (wm == hk) {
#pragma unroll
        for (int fn = 0; fn < 4; ++fn) {
          const int col = wn * 64 + fn * 16 + l16;
          const float bv = bias[n0 + col];
#pragma unroll
          for (int fm = 0; fm < 8; ++fm) {
            const int rl0 = fm * 16 + kg * 4;
#pragma unroll
            for (int i = 0; i < 4; ++i) {
              float v = acc[fm][fn][i] + bv;
              if (om == 0) { v *= SCALE_; v = fmaxf(v, 0.f) + EPS_FM_; }
              const int rl = rl0 + i;
              bf16 bvv = (bf16)v;
              *(unsigned short*)(lds + rl * 512 + ((((col >> 3) ^ (rl & 7))) << 4) +
                                 (col & 7) * 2) =
                  __builtin_bit_cast(unsigned short, bvv);
            }
          }
        }
      }
      __syncthreads();
#pragma unroll
      for (int it = 0; it < 8; ++it) {
        const int gi = it * 512 + tid;
        const int row = gi >> 5, g = gi & 31;
        bf16x8 v = *(const bf16x8*)(lds + row * 512 + ((g ^ (row & 7)) << 4));
        *(bf16x8*)(PbS + (size_t)(m0 + hk * 128 + row) * 1024 + n0 + g * 8) = v;
      }
      __syncthreads();
    }
  } else {
#pragma unroll
    for (int fn = 0; fn < 4; ++fn) {
      const int col = n0 + wn * 64 + fn * 16 + l16;
      const float bv = bias[col];
#pragma unroll
      for (int fm = 0; fm < 8; ++fm) {
        const int row = m0 + wm * 128 + fm * 16 + kg * 4;
#pragma unroll
        for (int i = 0; i < 4; ++i)
          Pf[(size_t)(row + i) * 1024 + col] = acc[fm][fn][i] + bv;
      }
    }
  }
}

// ---- KV via MFMA (unchanged)
__global__ __launch_bounds__(256) void kv_mfma(
    const bf16* __restrict__ Kp, const bf16* __restrict__ Vp,
    float* __restrict__ KVpart, float* __restrict__ KsumPart) {
  __shared__ __align__(16) char lds[65536];
  char* Kt = lds;
  char* Vt = lds + 32768;
  const int bh = blockIdx.x, split = blockIdx.y;
  const int b = bh >> 4, h = bh & 15;
  const int tid = threadIdx.x;
  const int p = tid >> 3, c = tid & 7;
  const int wave = tid >> 6, lane = tid & 63;
  const int wd = wave >> 1, we = wave & 1;
  const int l16 = lane & 15, kg = lane >> 4;
  f32x4 acc[2][2] = {};
  f32x4 accz[2] = {};
  const bf16x8 ones = {1.f, 1.f, 1.f, 1.f, 1.f, 1.f, 1.f, 1.f};

  for (int o = 0; o < 4; ++o) {
    const size_t gbase =
        (size_t)(b * 8192 + split * 1024 + o * 256) * 1024 + h * 64 + c * 8;
    __syncthreads();
#pragma unroll
    for (int i = 0; i < 4; ++i) {
      const int t = i * 64 + p * 2;
      const size_t ga = gbase + (size_t)t * 1024;
      bf16x8 k0 = *(const bf16x8*)(Kp + ga);
      bf16x8 k1 = *(const bf16x8*)(Kp + ga + 1024);
      bf16x8 v0 = *(const bf16x8*)(Vp + ga);
      bf16x8 v1 = *(const bf16x8*)(Vp + ga + 1024);
      u16x8 a0 = __builtin_bit_cast(u16x8, k0);
      u16x8 a1 = __builtin_bit_cast(u16x8, k1);
      u16x8 b0 = __builtin_bit_cast(u16x8, v0);
      u16x8 b1 = __builtin_bit_cast(u16x8, v1);
      const int gt = t >> 3, tl = (t & 7) * 2;
#pragma unroll
      for (int j = 0; j < 8; ++j) {
        const int d = c * 8 + j;
        const int off = d * 512 + ((gt ^ (d & 7) ^ c) << 4) + tl;
        *(unsigned int*)(Kt + off) =
            (unsigned int)a0[j] | ((unsigned int)a1[j] << 16);
        *(unsigned int*)(Vt + off) =
            (unsigned int)b0[j] | ((unsigned int)b1[j] << 16);
      }
    }
    __syncthreads();

#pragma unroll
    for (int ks = 0; ks < 8; ++ks) {
      const int g = ks * 4 + kg;
      bf16x8 af[2], bf_[2];
#pragma unroll
      for (int f = 0; f < 2; ++f) {
        const int d = wd * 32 + f * 16 + l16;
        af[f] = *(const bf16x8*)(Kt + d * 512 +
                                 ((g ^ (d & 7) ^ ((d >> 3) & 7)) << 4));
        const int ee = we * 32 + f * 16 + l16;
        bf_[f] = *(const bf16x8*)(Vt + ee * 512 +
                                  ((g ^ (ee & 7) ^ ((ee >> 3) & 7)) << 4));
      }
#pragma unroll
      for (int fa = 0; fa < 2; ++fa) {
#pragma unroll
        for (int fb = 0; fb < 2; ++fb)
          acc[fa][fb] = __builtin_amdgcn_mfma_f32_16x16x32_bf16(
              af[fa], bf_[fb], acc[fa][fb], 0, 0, 0);
        if (we == 0)
          accz[fa] = __builtin_amdgcn_mfma_f32_16x16x32_bf16(
              af[fa], ones, accz[fa], 0, 0, 0);
      }
    }
  }

  float* outp = KVpart + ((size_t)split * 64 + bh) * 4096;
#pragma unroll
  for (int fa = 0; fa < 2; ++fa)
#pragma unroll
    for (int i = 0; i < 4; ++i) {
      const int d = wd * 32 + fa * 16 + kg * 4 + i;
#pragma unroll
      for (int fb = 0; fb < 2; ++fb)
        outp[d * 64 + we * 32 + fb * 16 + l16] = acc[fa][fb][i];
      if (we == 0 && l16 == 0)
        KsumPart[((size_t)split * 64 + bh) * 64 + d] = accz[fa][i];
    }
}

// ---- reduce 8 split-partials -> KVt[bh][80][64] bf16 (unchanged)
__global__ __launch_bounds__(256) void kv_reduce(
    const float* __restrict__ KVpart, const float* __restrict__ KsumPart,
    bf16* __restrict__ KVt) {
  int bh = blockIdx.x;
  for (int idx = threadIdx.x; idx < 5120; idx += 256) {
    float s = 0.f;
    if (idx < 4096) {
      int e = idx >> 6, d = idx & 63;
      for (int sp = 0; sp < 8; ++sp)
        s += KVpart[((size_t)sp * 64 + bh) * 4096 + d * 64 + e];
    } else if (idx < 4160) {
      int d = idx - 4096;
      for (int sp = 0; sp < 8; ++sp)
        s += KsumPart[((size_t)sp * 64 + bh) * 64 + d];
    }
    KVt[(size_t)bh * 5120 + idx] = (bf16)s;
  }
}

// ---- attention (unchanged)
__global__ __launch_bounds__(256) void attn(
    const bf16* __restrict__ KVt, bf16* __restrict__ QA) {
  __shared__ __align__(16) char lds[43008];
  char* Qt = lds;
  char* Bt = lds + 32768;
  const int bh = blockIdx.x, tc = blockIdx.y;
  const int b = bh >> 4, h = bh & 15;
  const int tid = threadIdx.x;
  const int m0 = b * 8192 + tc * 256;

#pragma unroll
  for (int i = 0; i < 8; ++i) {
    const int gidx = i * 256 + tid;
    const int row = gidx >> 3, g = gidx & 7;
    const int gsrc = g ^ (row & 7);
    gl_lds16(QA + (size_t)(m0 + row) * 1024 + h * 64 + gsrc * 8, Qt + gidx * 16);
  }
#pragma unroll
  for (int i = 0; i < 3; ++i) {
    const int gidx = i * 256 + tid;
    if (gidx < 640) {
      const int row = gidx >> 3, g = gidx & 7;
      const int gsrc = g ^ (row & 7);
      gl_lds16(KVt + (size_t)bh * 5120 + row * 64 + gsrc * 8, Bt + gidx * 16);
    }
  }
  __syncthreads();

  const int wave = tid >> 6, lane = tid & 63;
  const int l16 = lane & 15, kg = lane >> 4;
  bf16x8 a[4][2];
#pragma unroll
  for (int fm = 0; fm < 4; ++fm)
#pragma unroll
    for (int kk = 0; kk < 2; ++kk) {
      const int row = wave * 64 + fm * 16 + l16;
      const int g = kk * 4 + kg;
      a[fm][kk] = *(const bf16x8*)(Qt + row * 128 + ((g ^ (row & 7)) << 4));
    }
  f32x4 acc[4][4] = {};
  f32x4 accz[4] = {};
#pragma unroll
  for (int kk = 0; kk < 2; ++kk) {
    const int g = kk * 4 + kg;
    const int zr = 64 + l16;
    bf16x8 bz = *(const bf16x8*)(Bt + zr * 128 + ((g ^ (zr & 7)) << 4));
#pragma unroll
    for (int fn = 0; fn < 4; ++fn) {
      const int br = fn * 16 + l16;
      bf16x8 bb = *(const bf16x8*)(Bt + br * 128 + ((g ^ (br & 7)) << 4));
#pragma unroll
      for (int fm = 0; fm < 4; ++fm)
        acc[fm][fn] = __builtin_amdgcn_mfma_f32_16x16x32_bf16(
            a[fm][kk], bb, acc[fm][fn], 0, 0, 0);
    }
#pragma unroll
    for (int fm = 0; fm < 4; ++fm)
      accz[fm] = __builtin_amdgcn_mfma_f32_16x16x32_bf16(
          a[fm][kk], bz, accz[fm], 0, 0, 0);
  }
  __syncthreads();

#pragma unroll
  for (int fm = 0; fm < 4; ++fm)
#pragma unroll
    for (int i = 0; i < 4; ++i) {
      const float z = __shfl(accz[fm][i], (lane & 48), 64) + EPS_Z_;
      const float rz = 1.0f / z;
      const int row = wave * 64 + fm * 16 + kg * 4 + i;
#pragma unroll
      for (int fn = 0; fn < 4; ++fn) {
        const int col = fn * 16 + l16;
        const int gc = col >> 3;
        bf16 v = (bf16)(acc[fm][fn][i] * rz);
        *(unsigned short*)(Qt + row * 128 + ((gc ^ (row & 7)) << 4) + (col & 7) * 2) =
            __builtin_bit_cast(unsigned short, v);
      }
    }
  __syncthreads();

#pragma unroll
  for (int i = 0; i < 8; ++i) {
    const int gidx = i * 256 + tid;
    const int row = gidx >> 3, g = gidx & 7;
    bf16x8 v = *(const bf16x8*)(Qt + row * 128 + ((g ^ (row & 7)) << 4));
    *(bf16x8*)(QA + (size_t)(m0 + row) * 1024 + h * 64 + g * 8) = v;
  }
}

extern "C" void kernel_launch(void* const* d_in, const int* in_sizes, int n_in,
                              void* d_out, int out_size, void* d_ws, size_t ws_size,
                              hipStream_t stream) {
  const float* query = (const float*)d_in[0];
  const float* key = (const float*)d_in[1];
  const float* value = (const float*)d_in[2];
  const float* Wq = (const float*)d_in[3];
  const float* bq = (const float*)d_in[4];
  const float* Wk = (const float*)d_in[5];
  const float* bk = (const float*)d_in[6];
  const float* Wv = (const float*)d_in[7];
  const float* bv = (const float*)d_in[8];
  const float* Wo = (const float*)d_in[9];
  const float* bo = (const float*)d_in[10];
  float* out = (float*)d_out;

  bf16* ws = (bf16*)d_ws;
  bf16* Wqb = ws;
  bf16* Wob = ws + (3u << 20);
  bf16* Qp = ws + (4u << 20);
  bf16* Kp = Qp + 33554432u;
  bf16* Vp = Kp + 33554432u;
  bf16* KVt = Vp + 33554432u;
  float* KVpart = (float*)d_out + 16777216u;      // 8 x 64 x 4096 fp32 = 8MB
  float* KsumPart = KVpart + 8 * 64 * 4096;       // 8 x 64 x 64 fp32

  cast_weights<<<dim3(1024, 4), 256, 0, stream>>>(Wq, Wk, Wv, Wo, Wqb);

  gemm8p<0><<<1536, 512, 0, stream>>>(nullptr, query, key, value, Wqb, bq, bk,
                                      bv, Qp, nullptr);

  kv_mfma<<<dim3(64, 8), 256, 0, stream>>>(Kp, Vp, KVpart, KsumPart);
  kv_reduce<<<64, 256, 0, stream>>>(KVpart, KsumPart, KVt);
  attn<<<dim3(64, 32), 256, 0, stream>>>(KVt, Qp);
  gemm8p<1><<<512, 512, 0, stream>>>(Qp, nullptr, nullptr, nullptr, Wob, bo,
                                     bo, bo, nullptr, out);
}

// Round 11
// 435.052 us; speedup vs baseline: 7.3632x; 7.3632x over previous
//
#include <hip/hip_runtime.h>
#include <hip/hip_bf16.h>

// LinearAttention: B=4, T=8192, E=1024, H=16, D=64
//
// R10: fix R9's launch-bounds disaster. hipcc treats __launch_bounds__' 2nd
// arg CUDA-style (min BLOCKS/CU): (512,4) forced a 64-VGPR cap -> 128-reg
// accumulator spilled to scratch (9.9GB traffic, 2464us). Revert to
// (512,2) = 128-VGPR cap (R2-R8 regime, no spill). With the 64KB
// single-buffered LDS (R9, ledger proven correct by its passing run),
// 2 blocks/CU now actually fit (16 waves x 128 VGPR, 128KB LDS total).
// Everything else byte-identical to R9.

#define SCALE_ 0.125f
#define EPS_FM_ 1e-6f
#define EPS_Z_ 1e-8f

typedef __bf16 bf16;
typedef __attribute__((ext_vector_type(4))) __bf16 bf16x4;
typedef __attribute__((ext_vector_type(8))) __bf16 bf16x8;
typedef __attribute__((ext_vector_type(8))) unsigned short u16x8;
typedef __attribute__((ext_vector_type(4))) float f32x4;

__device__ __forceinline__ void gl_lds16(const void* g, void* l) {
  __builtin_amdgcn_global_load_lds(
      (const __attribute__((address_space(1))) void*)g,
      (__attribute__((address_space(3))) void*)l, 16, 0, 0);
}

#define SBAR()                                  \
  do {                                          \
    __builtin_amdgcn_sched_barrier(0);          \
    asm volatile("s_barrier" ::: "memory");     \
    __builtin_amdgcn_sched_barrier(0);          \
  } while (0)

// ---- weights fp32 -> bf16 (4 matrices, one dispatch)
__global__ __launch_bounds__(256) void cast_weights(
    const float* __restrict__ Wq, const float* __restrict__ Wk,
    const float* __restrict__ Wv, const float* __restrict__ Wo,
    bf16* __restrict__ out) {
  int which = blockIdx.y;
  int j = (blockIdx.x * 256 + threadIdx.x) * 4;
  const float* s = (which == 0) ? Wq : (which == 1) ? Wk : (which == 2) ? Wv : Wo;
  float4 v = *(const float4*)(s + j);
  bf16x4 p = {(bf16)v.x, (bf16)v.y, (bf16)v.z, (bf16)v.w};
  *(bf16x4*)(out + (size_t)which * (1u << 20) + j) = p;
}

// ---- 256^2 8-phase GEMM, single-buffered LDS (64KB), 2 blocks/CU.
// MODE 0: fused 3-projection pass (A fp32, fused cast), grid 1536.
// MODE 1: output GEMM (A bf16 gl_lds, fp32 out), grid 512.
template <int MODE>
__global__ __launch_bounds__(512, 2) void gemm8p(
    const bf16* __restrict__ Ab, const float* __restrict__ Aq,
    const float* __restrict__ Ak, const float* __restrict__ Av,
    const bf16* __restrict__ Wb, const float* __restrict__ b0,
    const float* __restrict__ b1, const float* __restrict__ b2,
    bf16* __restrict__ Pb, float* __restrict__ Pf) {
  __shared__ __align__(16) char lds[65536];
  const int tid = threadIdx.x;
  const int bid = blockIdx.x;
  const int wg = (bid & 7) * (gridDim.x >> 3) + (bid >> 3);
  const int mt = wg >> 2;
  int seg = 0, om = 2;
  if constexpr (MODE == 0) {
    seg = mt >> 7;
    om = (seg < 2) ? 0 : 1;
  }
  const int m0 = (MODE == 0 ? (mt & 127) : mt) * 256;
  const int n0 = (wg & 3) * 256;
  const int wave = tid >> 6, lane = tid & 63;
  const int wm = wave >> 2, wn = wave & 3;
  const int l16 = lane & 15, kg = lane >> 4;
  const int e = l16 & 7;
  const int sw0 = (kg ^ e) << 4;
  const int sw1 = ((4 | kg) ^ e) << 4;

  const int tr = tid >> 3;
  const int cslot = (tid & 7) ^ (tr & 7);
  const bf16* pA = nullptr;
  const float* pAf = nullptr;
  if constexpr (MODE == 1)
    pA = Ab + (size_t)(m0 + tr) * 1024 + cslot * 8;
  else {
    const float* Af = (seg == 0) ? Aq : (seg == 1) ? Ak : Av;
    pAf = Af + (size_t)(m0 + tr) * 1024 + cslot * 8;
  }
  const bf16* W = (MODE == 0) ? Wb + ((size_t)seg << 20) : Wb;
  const float* bias = (MODE == 0) ? ((seg == 0) ? b0 : (seg == 1) ? b1 : b2) : b0;
  const bf16* pB = W + (size_t)(n0 + ((tr >> 5) << 6) + (tr & 31)) * 1024 + cslot * 8;
  char* sA = lds;            // A03 region [0,16K), A47 [16K,32K)
  char* sB = lds + 32768;    // B01 [32K,48K), B23 [48K,64K)

  auto stgA = [&](int h, int kt) {  // MODE1
    const bf16* g = pA + h * 65536 + kt * 64;
    char* d = sA + h * 16384 + tid * 16;
    gl_lds16(g, d);
    gl_lds16(g + 131072, d + 8192);
  };
  auto stgB = [&](int h, int kt) {
    const bf16* g = pB + h * 32768 + kt * 64;
    char* d = sB + h * 16384 + tid * 16;
    gl_lds16(g, d);
    gl_lds16(g + 131072, d + 8192);
  };
  // MODE0: reg-staged fused cast
  auto ldgA = [&](int h, int kt, f32x4* r) {
    const float* g = pAf + h * 65536 + kt * 64;
    r[0] = *(const f32x4*)g;
    r[1] = *(const f32x4*)(g + 4);
    r[2] = *(const f32x4*)(g + 131072);
    r[3] = *(const f32x4*)(g + 131072 + 4);
  };
  auto wrA = [&](int h, const f32x4* r) {
    bf16x8 p0 = {(bf16)r[0][0], (bf16)r[0][1], (bf16)r[0][2], (bf16)r[0][3],
                 (bf16)r[1][0], (bf16)r[1][1], (bf16)r[1][2], (bf16)r[1][3]};
    bf16x8 p1 = {(bf16)r[2][0], (bf16)r[2][1], (bf16)r[2][2], (bf16)r[2][3],
                 (bf16)r[3][0], (bf16)r[3][1], (bf16)r[3][2], (bf16)r[3][3]};
    char* d = sA + h * 16384 + tid * 16;
    *(bf16x8*)d = p0;
    *(bf16x8*)(d + 8192) = p1;
  };

  const int aBase = wm * 8192 + l16 * 128;
  const int bBase = wn * 4096 + l16 * 128;
  auto ldA = [&](int h, int fmi, int kk) {
    return *(const bf16x8*)(sA + h * 16384 + aBase + fmi * 2048 +
                            (kk ? sw1 : sw0));
  };
  auto ldB = [&](int h, int fnj, int kk) {
    return *(const bf16x8*)(sB + h * 16384 + bBase + fnj * 2048 +
                            (kk ? sw1 : sw0));
  };

  f32x4 acc[8][4] = {};
  bf16x8 rA[4][2], rB01[2][2], rB23[2][2];
  f32x4 ga[4], gb[4];
  const int NT = 16;

  if constexpr (MODE == 1) {
    // prologue: tile 0 all regions; A47 guarded later by t0.ph2-end vmcnt(4)
    stgA(0, 0); stgB(0, 0); stgB(1, 0); stgA(1, 0);
    asm volatile("s_waitcnt vmcnt(2)" ::: "memory");
  } else {
    ldgA(0, 0, ga); ldgA(1, 0, gb);
    stgB(0, 0); stgB(1, 0);
    asm volatile("s_waitcnt vmcnt(12)" ::: "memory");
    wrA(0, ga);
    asm volatile("s_waitcnt vmcnt(4)" ::: "memory");
    wrA(1, gb);
    ldgA(0, 1, ga); ldgA(1, 1, gb);
    asm volatile("s_waitcnt vmcnt(16)" ::: "memory");  // B01(0),B23(0) landed
    asm volatile("s_waitcnt lgkmcnt(0)" ::: "memory");
  }
  SBAR();

#pragma unroll 2
  for (int t = 0; t < NT; ++t) {
    // ---- ph1: read A03+B01 (no stages)
#pragma unroll
    for (int fmi = 0; fmi < 4; ++fmi) {
      rA[fmi][0] = ldA(0, fmi, 0);
      rA[fmi][1] = ldA(0, fmi, 1);
    }
#pragma unroll
    for (int fnj = 0; fnj < 2; ++fnj) {
      rB01[fnj][0] = ldB(0, fnj, 0);
      rB01[fnj][1] = ldB(0, fnj, 1);
    }
    SBAR();
    __builtin_amdgcn_s_setprio(1);
#pragma unroll
    for (int fmi = 0; fmi < 4; ++fmi)
#pragma unroll
      for (int fnj = 0; fnj < 2; ++fnj)
#pragma unroll
        for (int kk = 0; kk < 2; ++kk)
          acc[fmi][fnj] = __builtin_amdgcn_mfma_f32_16x16x32_bf16(
              rA[fmi][kk], rB01[fnj][kk], acc[fmi][fnj], 0, 0, 0);
    __builtin_amdgcn_s_setprio(0);
    SBAR();
    // ---- ph2: read B23; stage B01(t+1) (+A03(t+1) MODE1)
#pragma unroll
    for (int fnj = 0; fnj < 2; ++fnj) {
      rB23[fnj][0] = ldB(1, fnj, 0);
      rB23[fnj][1] = ldB(1, fnj, 1);
    }
    if (t + 1 < NT) {
      if constexpr (MODE == 1) stgA(0, t + 1);
      stgB(0, t + 1);
    }
    SBAR();
    __builtin_amdgcn_s_setprio(1);
#pragma unroll
    for (int fmi = 0; fmi < 4; ++fmi)
#pragma unroll
      for (int fnj = 0; fnj < 2; ++fnj)
#pragma unroll
        for (int kk = 0; kk < 2; ++kk)
          acc[fmi][2 + fnj] = __builtin_amdgcn_mfma_f32_16x16x32_bf16(
              rA[fmi][kk], rB23[fnj][kk], acc[fmi][2 + fnj], 0, 0, 0);
    __builtin_amdgcn_s_setprio(0);
    __builtin_amdgcn_sched_barrier(0);
    if constexpr (MODE == 1) {  // guard A47(t) (staged (t-1).ph4) before ph3 reads
      if (t + 1 < NT)
        asm volatile("s_waitcnt vmcnt(4)" ::: "memory");
      else
        asm volatile("s_waitcnt vmcnt(0)" ::: "memory");
    }
    SBAR();
    // ---- ph3: read A47; stage B23(t+1); MODE0 post: wrA03(t+1)+ldgA03(t+2)
#pragma unroll
    for (int fmi = 0; fmi < 4; ++fmi) {
      rA[fmi][0] = ldA(1, fmi, 0);
      rA[fmi][1] = ldA(1, fmi, 1);
    }
    if (t + 1 < NT) stgB(1, t + 1);
    SBAR();
    __builtin_amdgcn_s_setprio(1);
#pragma unroll
    for (int fmi = 0; fmi < 4; ++fmi)
#pragma unroll
      for (int fnj = 0; fnj < 2; ++fnj)
#pragma unroll
        for (int kk = 0; kk < 2; ++kk)
          acc[4 + fmi][2 + fnj] = __builtin_amdgcn_mfma_f32_16x16x32_bf16(
              rA[fmi][kk], rB23[fnj][kk], acc[4 + fmi][2 + fnj], 0, 0, 0);
    __builtin_amdgcn_s_setprio(0);
    __builtin_amdgcn_sched_barrier(0);
    if constexpr (MODE == 0) {
      if (t + 1 < NT) {
        wrA(0, ga);
        if (t + 2 < NT) ldgA(0, t + 2, ga);
      }
    }
    SBAR();
    // ---- ph4: MODE1 stage A47(t+1); MFMA A47xB01(regs); MODE0 post:
    //           wrA47(t+1)+ldgA47(t+2); tile-boundary vmcnt; SBAR
    if constexpr (MODE == 1) {
      if (t + 1 < NT) stgA(1, t + 1);
    }
    SBAR();
    __builtin_amdgcn_s_setprio(1);
#pragma unroll
    for (int fmi = 0; fmi < 4; ++fmi)
#pragma unroll
      for (int fnj = 0; fnj < 2; ++fnj)
#pragma unroll
        for (int kk = 0; kk < 2; ++kk)
          acc[4 + fmi][fnj] = __builtin_amdgcn_mfma_f32_16x16x32_bf16(
              rA[fmi][kk], rB01[fnj][kk], acc[4 + fmi][fnj], 0, 0, 0);
    __builtin_amdgcn_s_setprio(0);
    __builtin_amdgcn_sched_barrier(0);
    if constexpr (MODE == 0) {
      if (t + 1 < NT) {
        wrA(1, gb);
        if (t + 2 < NT) ldgA(1, t + 2, gb);
        if (t + 2 < NT)
          asm volatile("s_waitcnt vmcnt(16)" ::: "memory");
        else
          asm volatile("s_waitcnt vmcnt(0)" ::: "memory");
      }
    } else {
      if (t + 1 < NT)
        asm volatile("s_waitcnt vmcnt(2)" ::: "memory");
    }
    SBAR();
  }

  // ---- epilogue
  if constexpr (MODE == 0) {
    // C-bounce in 2 chunks of 64KB (rows wm*128..): coalesced 512B stores.
    bf16* PbS = Pb + (size_t)seg * 33554432u;
#pragma unroll
    for (int hk = 0; hk < 2; ++hk) {
      if (wm == hk) {
#pragma unroll
        for (int fn = 0; fn < 4; ++fn) {
          const int col = wn * 64 + fn * 16 + l16;
          const float bv = bias[n0 + col];
#pragma unroll
          for (int fm = 0; fm < 8; ++fm) {
            const int rl0 = fm * 16 + kg * 4;
#pragma unroll
            for (int i = 0; i < 4; ++i) {
              float v = acc[fm][fn][i] + bv;
              if (om == 0) { v *= SCALE_; v = fmaxf(v, 0.f) + EPS_FM_; }
              const int rl = rl0 + i;
              bf16 bvv = (bf16)v;
              *(unsigned short*)(lds + rl * 512 + ((((col >> 3) ^ (rl & 7))) << 4) +
                                 (col & 7) * 2) =
                  __builtin_bit_cast(unsigned short, bvv);
            }
          }
        }
      }
      __syncthreads();
#pragma unroll
      for (int it = 0; it < 8; ++it) {
        const int gi = it * 512 + tid;
        const int row = gi >> 5, g = gi & 31;
        bf16x8 v = *(const bf16x8*)(lds + row * 512 + ((g ^ (row & 7)) << 4));
        *(bf16x8*)(PbS + (size_t)(m0 + hk * 128 + row) * 1024 + n0 + g * 8) = v;
      }
      __syncthreads();
    }
  } else {
#pragma unroll
    for (int fn = 0; fn < 4; ++fn) {
      const int col = n0 + wn * 64 + fn * 16 + l16;
      const float bv = bias[col];
#pragma unroll
      for (int fm = 0; fm < 8; ++fm) {
        const int row = m0 + wm * 128 + fm * 16 + kg * 4;
#pragma unroll
        for (int i = 0; i < 4; ++i)
          Pf[(size_t)(row + i) * 1024 + col] = acc[fm][fn][i] + bv;
      }
    }
  }
}

// ---- KV via MFMA (unchanged)
__global__ __launch_bounds__(256) void kv_mfma(
    const bf16* __restrict__ Kp, const bf16* __restrict__ Vp,
    float* __restrict__ KVpart, float* __restrict__ KsumPart) {
  __shared__ __align__(16) char lds[65536];
  char* Kt = lds;
  char* Vt = lds + 32768;
  const int bh = blockIdx.x, split = blockIdx.y;
  const int b = bh >> 4, h = bh & 15;
  const int tid = threadIdx.x;
  const int p = tid >> 3, c = tid & 7;
  const int wave = tid >> 6, lane = tid & 63;
  const int wd = wave >> 1, we = wave & 1;
  const int l16 = lane & 15, kg = lane >> 4;
  f32x4 acc[2][2] = {};
  f32x4 accz[2] = {};
  const bf16x8 ones = {1.f, 1.f, 1.f, 1.f, 1.f, 1.f, 1.f, 1.f};

  for (int o = 0; o < 4; ++o) {
    const size_t gbase =
        (size_t)(b * 8192 + split * 1024 + o * 256) * 1024 + h * 64 + c * 8;
    __syncthreads();
#pragma unroll
    for (int i = 0; i < 4; ++i) {
      const int t = i * 64 + p * 2;
      const size_t ga = gbase + (size_t)t * 1024;
      bf16x8 k0 = *(const bf16x8*)(Kp + ga);
      bf16x8 k1 = *(const bf16x8*)(Kp + ga + 1024);
      bf16x8 v0 = *(const bf16x8*)(Vp + ga);
      bf16x8 v1 = *(const bf16x8*)(Vp + ga + 1024);
      u16x8 a0 = __builtin_bit_cast(u16x8, k0);
      u16x8 a1 = __builtin_bit_cast(u16x8, k1);
      u16x8 b0 = __builtin_bit_cast(u16x8, v0);
      u16x8 b1 = __builtin_bit_cast(u16x8, v1);
      const int gt = t >> 3, tl = (t & 7) * 2;
#pragma unroll
      for (int j = 0; j < 8; ++j) {
        const int d = c * 8 + j;
        const int off = d * 512 + ((gt ^ (d & 7) ^ c) << 4) + tl;
        *(unsigned int*)(Kt + off) =
            (unsigned int)a0[j] | ((unsigned int)a1[j] << 16);
        *(unsigned int*)(Vt + off) =
            (unsigned int)b0[j] | ((unsigned int)b1[j] << 16);
      }
    }
    __syncthreads();

#pragma unroll
    for (int ks = 0; ks < 8; ++ks) {
      const int g = ks * 4 + kg;
      bf16x8 af[2], bf_[2];
#pragma unroll
      for (int f = 0; f < 2; ++f) {
        const int d = wd * 32 + f * 16 + l16;
        af[f] = *(const bf16x8*)(Kt + d * 512 +
                                 ((g ^ (d & 7) ^ ((d >> 3) & 7)) << 4));
        const int ee = we * 32 + f * 16 + l16;
        bf_[f] = *(const bf16x8*)(Vt + ee * 512 +
                                  ((g ^ (ee & 7) ^ ((ee >> 3) & 7)) << 4));
      }
#pragma unroll
      for (int fa = 0; fa < 2; ++fa) {
#pragma unroll
        for (int fb = 0; fb < 2; ++fb)
          acc[fa][fb] = __builtin_amdgcn_mfma_f32_16x16x32_bf16(
              af[fa], bf_[fb], acc[fa][fb], 0, 0, 0);
        if (we == 0)
          accz[fa] = __builtin_amdgcn_mfma_f32_16x16x32_bf16(
              af[fa], ones, accz[fa], 0, 0, 0);
      }
    }
  }

  float* outp = KVpart + ((size_t)split * 64 + bh) * 4096;
#pragma unroll
  for (int fa = 0; fa < 2; ++fa)
#pragma unroll
    for (int i = 0; i < 4; ++i) {
      const int d = wd * 32 + fa * 16 + kg * 4 + i;
#pragma unroll
      for (int fb = 0; fb < 2; ++fb)
        outp[d * 64 + we * 32 + fb * 16 + l16] = acc[fa][fb][i];
      if (we == 0 && l16 == 0)
        KsumPart[((size_t)split * 64 + bh) * 64 + d] = accz[fa][i];
    }
}

// ---- reduce 8 split-partials -> KVt[bh][80][64] bf16 (unchanged)
__global__ __launch_bounds__(256) void kv_reduce(
    const float* __restrict__ KVpart, const float* __restrict__ KsumPart,
    bf16* __restrict__ KVt) {
  int bh = blockIdx.x;
  for (int idx = threadIdx.x; idx < 5120; idx += 256) {
    float s = 0.f;
    if (idx < 4096) {
      int e = idx >> 6, d = idx & 63;
      for (int sp = 0; sp < 8; ++sp)
        s += KVpart[((size_t)sp * 64 + bh) * 4096 + d * 64 + e];
    } else if (idx < 4160) {
      int d = idx - 4096;
      for (int sp = 0; sp < 8; ++sp)
        s += KsumPart[((size_t)sp * 64 + bh) * 64 + d];
    }
    KVt[(size_t)bh * 5120 + idx] = (bf16)s;
  }
}

// ---- attention (unchanged)
__global__ __launch_bounds__(256) void attn(
    const bf16* __restrict__ KVt, bf16* __restrict__ QA) {
  __shared__ __align__(16) char lds[43008];
  char* Qt = lds;
  char* Bt = lds + 32768;
  const int bh = blockIdx.x, tc = blockIdx.y;
  const int b = bh >> 4, h = bh & 15;
  const int tid = threadIdx.x;
  const int m0 = b * 8192 + tc * 256;

#pragma unroll
  for (int i = 0; i < 8; ++i) {
    const int gidx = i * 256 + tid;
    const int row = gidx >> 3, g = gidx & 7;
    const int gsrc = g ^ (row & 7);
    gl_lds16(QA + (size_t)(m0 + row) * 1024 + h * 64 + gsrc * 8, Qt + gidx * 16);
  }
#pragma unroll
  for (int i = 0; i < 3; ++i) {
    const int gidx = i * 256 + tid;
    if (gidx < 640) {
      const int row = gidx >> 3, g = gidx & 7;
      const int gsrc = g ^ (row & 7);
      gl_lds16(KVt + (size_t)bh * 5120 + row * 64 + gsrc * 8, Bt + gidx * 16);
    }
  }
  __syncthreads();

  const int wave = tid >> 6, lane = tid & 63;
  const int l16 = lane & 15, kg = lane >> 4;
  bf16x8 a[4][2];
#pragma unroll
  for (int fm = 0; fm < 4; ++fm)
#pragma unroll
    for (int kk = 0; kk < 2; ++kk) {
      const int row = wave * 64 + fm * 16 + l16;
      const int g = kk * 4 + kg;
      a[fm][kk] = *(const bf16x8*)(Qt + row * 128 + ((g ^ (row & 7)) << 4));
    }
  f32x4 acc[4][4] = {};
  f32x4 accz[4] = {};
#pragma unroll
  for (int kk = 0; kk < 2; ++kk) {
    const int g = kk * 4 + kg;
    const int zr = 64 + l16;
    bf16x8 bz = *(const bf16x8*)(Bt + zr * 128 + ((g ^ (zr & 7)) << 4));
#pragma unroll
    for (int fn = 0; fn < 4; ++fn) {
      const int br = fn * 16 + l16;
      bf16x8 bb = *(const bf16x8*)(Bt + br * 128 + ((g ^ (br & 7)) << 4));
#pragma unroll
      for (int fm = 0; fm < 4; ++fm)
        acc[fm][fn] = __builtin_amdgcn_mfma_f32_16x16x32_bf16(
            a[fm][kk], bb, acc[fm][fn], 0, 0, 0);
    }
#pragma unroll
    for (int fm = 0; fm < 4; ++fm)
      accz[fm] = __builtin_amdgcn_mfma_f32_16x16x32_bf16(
          a[fm][kk], bz, accz[fm], 0, 0, 0);
  }
  __syncthreads();

#pragma unroll
  for (int fm = 0; fm < 4; ++fm)
#pragma unroll
    for (int i = 0; i < 4; ++i) {
      const float z = __shfl(accz[fm][i], (lane & 48), 64) + EPS_Z_;
      const float rz = 1.0f / z;
      const int row = wave * 64 + fm * 16 + kg * 4 + i;
#pragma unroll
      for (int fn = 0; fn < 4; ++fn) {
        const int col = fn * 16 + l16;
        const int gc = col >> 3;
        bf16 v = (bf16)(acc[fm][fn][i] * rz);
        *(unsigned short*)(Qt + row * 128 + ((gc ^ (row & 7)) << 4) + (col & 7) * 2) =
            __builtin_bit_cast(unsigned short, v);
      }
    }
  __syncthreads();

#pragma unroll
  for (int i = 0; i < 8; ++i) {
    const int gidx = i * 256 + tid;
    const int row = gidx >> 3, g = gidx & 7;
    bf16x8 v = *(const bf16x8*)(Qt + row * 128 + ((g ^ (row & 7)) << 4));
    *(bf16x8*)(QA + (size_t)(m0 + row) * 1024 + h * 64 + g * 8) = v;
  }
}

extern "C" void kernel_launch(void* const* d_in, const int* in_sizes, int n_in,
                              void* d_out, int out_size, void* d_ws, size_t ws_size,
                              hipStream_t stream) {
  const float* query = (const float*)d_in[0];
  const float* key = (const float*)d_in[1];
  const float* value = (const float*)d_in[2];
  const float* Wq = (const float*)d_in[3];
  const float* bq = (const float*)d_in[4];
  const float* Wk = (const float*)d_in[5];
  const float* bk = (const float*)d_in[6];
  const float* Wv = (const float*)d_in[7];
  const float* bv = (const float*)d_in[8];
  const float* Wo = (const float*)d_in[9];
  const float* bo = (const float*)d_in[10];
  float* out = (float*)d_out;

  bf16* ws = (bf16*)d_ws;
  bf16* Wqb = ws;
  bf16* Wob = ws + (3u << 20);
  bf16* Qp = ws + (4u << 20);
  bf16* Kp = Qp + 33554432u;
  bf16* Vp = Kp + 33554432u;
  bf16* KVt = Vp + 33554432u;
  float* KVpart = (float*)d_out + 16777216u;      // 8 x 64 x 4096 fp32 = 8MB
  float* KsumPart = KVpart + 8 * 64 * 4096;       // 8 x 64 x 64 fp32

  cast_weights<<<dim3(1024, 4), 256, 0, stream>>>(Wq, Wk, Wv, Wo, Wqb);

  gemm8p<0><<<1536, 512, 0, stream>>>(nullptr, query, key, value, Wqb, bq, bk,
                                      bv, Qp, nullptr);

  kv_mfma<<<dim3(64, 8), 256, 0, stream>>>(Kp, Vp, KVpart, KsumPart);
  kv_reduce<<<64, 256, 0, stream>>>(KVpart, KsumPart, KVt);
  attn<<<dim3(64, 32), 256, 0, stream>>>(KVt, Qp);
  gemm8p<1><<<512, 512, 0, stream>>>(Qp, nullptr, nullptr, nullptr, Wob, bo,
                                     bo, bo, nullptr, out);
}

// Round 12
// 428.049 us; speedup vs baseline: 7.4836x; 1.0164x over previous
//
#include <hip/hip_runtime.h>
#include <hip/hip_bf16.h>

// LinearAttention: B=4, T=8192, E=1024, H=16, D=64
//
// R11: (a) MODE0 vmcnt 16->8 (prologue + ph4): the 16s were no-ops
//      (outstanding=12), leaving the B-stage drain to luck. 8 = keep the
//      8 in-flight ldgA, drain both stgB pairs. Closes a latent race.
//      (b) kv_mfma: T14 reg-prefetch - chunk o+1's global loads issued
//      after the post-scatter barrier, overlapping chunk o's MFMA.
//      (c) kv_reduce: grid 64->256 (4 blocks per bh).
// GEMM structure / attn otherwise byte-identical to R10.

#define SCALE_ 0.125f
#define EPS_FM_ 1e-6f
#define EPS_Z_ 1e-8f

typedef __bf16 bf16;
typedef __attribute__((ext_vector_type(4))) __bf16 bf16x4;
typedef __attribute__((ext_vector_type(8))) __bf16 bf16x8;
typedef __attribute__((ext_vector_type(8))) unsigned short u16x8;
typedef __attribute__((ext_vector_type(4))) float f32x4;

__device__ __forceinline__ void gl_lds16(const void* g, void* l) {
  __builtin_amdgcn_global_load_lds(
      (const __attribute__((address_space(1))) void*)g,
      (__attribute__((address_space(3))) void*)l, 16, 0, 0);
}

#define SBAR()                                  \
  do {                                          \
    __builtin_amdgcn_sched_barrier(0);          \
    asm volatile("s_barrier" ::: "memory");     \
    __builtin_amdgcn_sched_barrier(0);          \
  } while (0)

// ---- weights fp32 -> bf16 (4 matrices, one dispatch)
__global__ __launch_bounds__(256) void cast_weights(
    const float* __restrict__ Wq, const float* __restrict__ Wk,
    const float* __restrict__ Wv, const float* __restrict__ Wo,
    bf16* __restrict__ out) {
  int which = blockIdx.y;
  int j = (blockIdx.x * 256 + threadIdx.x) * 4;
  const float* s = (which == 0) ? Wq : (which == 1) ? Wk : (which == 2) ? Wv : Wo;
  float4 v = *(const float4*)(s + j);
  bf16x4 p = {(bf16)v.x, (bf16)v.y, (bf16)v.z, (bf16)v.w};
  *(bf16x4*)(out + (size_t)which * (1u << 20) + j) = p;
}

// ---- 256^2 8-phase GEMM, single-buffered LDS (64KB).
// MODE 0: fused 3-projection pass (A fp32, fused cast), grid 1536.
// MODE 1: output GEMM (A bf16 gl_lds, fp32 out), grid 512.
template <int MODE>
__global__ __launch_bounds__(512, 2) void gemm8p(
    const bf16* __restrict__ Ab, const float* __restrict__ Aq,
    const float* __restrict__ Ak, const float* __restrict__ Av,
    const bf16* __restrict__ Wb, const float* __restrict__ b0,
    const float* __restrict__ b1, const float* __restrict__ b2,
    bf16* __restrict__ Pb, float* __restrict__ Pf) {
  __shared__ __align__(16) char lds[65536];
  const int tid = threadIdx.x;
  const int bid = blockIdx.x;
  const int wg = (bid & 7) * (gridDim.x >> 3) + (bid >> 3);
  const int mt = wg >> 2;
  int seg = 0, om = 2;
  if constexpr (MODE == 0) {
    seg = mt >> 7;
    om = (seg < 2) ? 0 : 1;
  }
  const int m0 = (MODE == 0 ? (mt & 127) : mt) * 256;
  const int n0 = (wg & 3) * 256;
  const int wave = tid >> 6, lane = tid & 63;
  const int wm = wave >> 2, wn = wave & 3;
  const int l16 = lane & 15, kg = lane >> 4;
  const int e = l16 & 7;
  const int sw0 = (kg ^ e) << 4;
  const int sw1 = ((4 | kg) ^ e) << 4;

  const int tr = tid >> 3;
  const int cslot = (tid & 7) ^ (tr & 7);
  const bf16* pA = nullptr;
  const float* pAf = nullptr;
  if constexpr (MODE == 1)
    pA = Ab + (size_t)(m0 + tr) * 1024 + cslot * 8;
  else {
    const float* Af = (seg == 0) ? Aq : (seg == 1) ? Ak : Av;
    pAf = Af + (size_t)(m0 + tr) * 1024 + cslot * 8;
  }
  const bf16* W = (MODE == 0) ? Wb + ((size_t)seg << 20) : Wb;
  const float* bias = (MODE == 0) ? ((seg == 0) ? b0 : (seg == 1) ? b1 : b2) : b0;
  const bf16* pB = W + (size_t)(n0 + ((tr >> 5) << 6) + (tr & 31)) * 1024 + cslot * 8;
  char* sA = lds;            // A03 region [0,16K), A47 [16K,32K)
  char* sB = lds + 32768;    // B01 [32K,48K), B23 [48K,64K)

  auto stgA = [&](int h, int kt) {  // MODE1
    const bf16* g = pA + h * 65536 + kt * 64;
    char* d = sA + h * 16384 + tid * 16;
    gl_lds16(g, d);
    gl_lds16(g + 131072, d + 8192);
  };
  auto stgB = [&](int h, int kt) {
    const bf16* g = pB + h * 32768 + kt * 64;
    char* d = sB + h * 16384 + tid * 16;
    gl_lds16(g, d);
    gl_lds16(g + 131072, d + 8192);
  };
  // MODE0: reg-staged fused cast
  auto ldgA = [&](int h, int kt, f32x4* r) {
    const float* g = pAf + h * 65536 + kt * 64;
    r[0] = *(const f32x4*)g;
    r[1] = *(const f32x4*)(g + 4);
    r[2] = *(const f32x4*)(g + 131072);
    r[3] = *(const f32x4*)(g + 131072 + 4);
  };
  auto wrA = [&](int h, const f32x4* r) {
    bf16x8 p0 = {(bf16)r[0][0], (bf16)r[0][1], (bf16)r[0][2], (bf16)r[0][3],
                 (bf16)r[1][0], (bf16)r[1][1], (bf16)r[1][2], (bf16)r[1][3]};
    bf16x8 p1 = {(bf16)r[2][0], (bf16)r[2][1], (bf16)r[2][2], (bf16)r[2][3],
                 (bf16)r[3][0], (bf16)r[3][1], (bf16)r[3][2], (bf16)r[3][3]};
    char* d = sA + h * 16384 + tid * 16;
    *(bf16x8*)d = p0;
    *(bf16x8*)(d + 8192) = p1;
  };

  const int aBase = wm * 8192 + l16 * 128;
  const int bBase = wn * 4096 + l16 * 128;
  auto ldA = [&](int h, int fmi, int kk) {
    return *(const bf16x8*)(sA + h * 16384 + aBase + fmi * 2048 +
                            (kk ? sw1 : sw0));
  };
  auto ldB = [&](int h, int fnj, int kk) {
    return *(const bf16x8*)(sB + h * 16384 + bBase + fnj * 2048 +
                            (kk ? sw1 : sw0));
  };

  f32x4 acc[8][4] = {};
  bf16x8 rA[4][2], rB01[2][2], rB23[2][2];
  f32x4 ga[4], gb[4];
  const int NT = 16;

  if constexpr (MODE == 1) {
    stgA(0, 0); stgB(0, 0); stgB(1, 0); stgA(1, 0);
    asm volatile("s_waitcnt vmcnt(2)" ::: "memory");
  } else {
    ldgA(0, 0, ga); ldgA(1, 0, gb);
    stgB(0, 0); stgB(1, 0);
    asm volatile("s_waitcnt vmcnt(12)" ::: "memory");
    wrA(0, ga);
    asm volatile("s_waitcnt vmcnt(4)" ::: "memory");
    wrA(1, gb);
    ldgA(0, 1, ga); ldgA(1, 1, gb);
    // drain stgB(0,0)/stgB(1,0) (all ops older than the 8 ldgA just issued)
    asm volatile("s_waitcnt vmcnt(8)" ::: "memory");
    asm volatile("s_waitcnt lgkmcnt(0)" ::: "memory");
  }
  SBAR();

#pragma unroll 2
  for (int t = 0; t < NT; ++t) {
    // ---- ph1: read A03+B01 (no stages)
#pragma unroll
    for (int fmi = 0; fmi < 4; ++fmi) {
      rA[fmi][0] = ldA(0, fmi, 0);
      rA[fmi][1] = ldA(0, fmi, 1);
    }
#pragma unroll
    for (int fnj = 0; fnj < 2; ++fnj) {
      rB01[fnj][0] = ldB(0, fnj, 0);
      rB01[fnj][1] = ldB(0, fnj, 1);
    }
    SBAR();
    __builtin_amdgcn_s_setprio(1);
#pragma unroll
    for (int fmi = 0; fmi < 4; ++fmi)
#pragma unroll
      for (int fnj = 0; fnj < 2; ++fnj)
#pragma unroll
        for (int kk = 0; kk < 2; ++kk)
          acc[fmi][fnj] = __builtin_amdgcn_mfma_f32_16x16x32_bf16(
              rA[fmi][kk], rB01[fnj][kk], acc[fmi][fnj], 0, 0, 0);
    __builtin_amdgcn_s_setprio(0);
    SBAR();
    // ---- ph2: read B23; stage B01(t+1) (+A03(t+1) MODE1)
#pragma unroll
    for (int fnj = 0; fnj < 2; ++fnj) {
      rB23[fnj][0] = ldB(1, fnj, 0);
      rB23[fnj][1] = ldB(1, fnj, 1);
    }
    if (t + 1 < NT) {
      if constexpr (MODE == 1) stgA(0, t + 1);
      stgB(0, t + 1);
    }
    SBAR();
    __builtin_amdgcn_s_setprio(1);
#pragma unroll
    for (int fmi = 0; fmi < 4; ++fmi)
#pragma unroll
      for (int fnj = 0; fnj < 2; ++fnj)
#pragma unroll
        for (int kk = 0; kk < 2; ++kk)
          acc[fmi][2 + fnj] = __builtin_amdgcn_mfma_f32_16x16x32_bf16(
              rA[fmi][kk], rB23[fnj][kk], acc[fmi][2 + fnj], 0, 0, 0);
    __builtin_amdgcn_s_setprio(0);
    __builtin_amdgcn_sched_barrier(0);
    if constexpr (MODE == 1) {  // guard A47(t) (staged (t-1).ph4) before ph3 reads
      if (t + 1 < NT)
        asm volatile("s_waitcnt vmcnt(4)" ::: "memory");
      else
        asm volatile("s_waitcnt vmcnt(0)" ::: "memory");
    }
    SBAR();
    // ---- ph3: read A47; stage B23(t+1); MODE0 post: wrA03(t+1)+ldgA03(t+2)
#pragma unroll
    for (int fmi = 0; fmi < 4; ++fmi) {
      rA[fmi][0] = ldA(1, fmi, 0);
      rA[fmi][1] = ldA(1, fmi, 1);
    }
    if (t + 1 < NT) stgB(1, t + 1);
    SBAR();
    __builtin_amdgcn_s_setprio(1);
#pragma unroll
    for (int fmi = 0; fmi < 4; ++fmi)
#pragma unroll
      for (int fnj = 0; fnj < 2; ++fnj)
#pragma unroll
        for (int kk = 0; kk < 2; ++kk)
          acc[4 + fmi][2 + fnj] = __builtin_amdgcn_mfma_f32_16x16x32_bf16(
              rA[fmi][kk], rB23[fnj][kk], acc[4 + fmi][2 + fnj], 0, 0, 0);
    __builtin_amdgcn_s_setprio(0);
    __builtin_amdgcn_sched_barrier(0);
    if constexpr (MODE == 0) {
      if (t + 1 < NT) {
        wrA(0, ga);
        if (t + 2 < NT) ldgA(0, t + 2, ga);
      }
    }
    SBAR();
    // ---- ph4: MODE1 stage A47(t+1); MFMA A47xB01(regs); MODE0 post:
    //           wrA47(t+1)+ldgA47(t+2); tile-boundary vmcnt; SBAR
    if constexpr (MODE == 1) {
      if (t + 1 < NT) stgA(1, t + 1);
    }
    SBAR();
    __builtin_amdgcn_s_setprio(1);
#pragma unroll
    for (int fmi = 0; fmi < 4; ++fmi)
#pragma unroll
      for (int fnj = 0; fnj < 2; ++fnj)
#pragma unroll
        for (int kk = 0; kk < 2; ++kk)
          acc[4 + fmi][fnj] = __builtin_amdgcn_mfma_f32_16x16x32_bf16(
              rA[fmi][kk], rB01[fnj][kk], acc[4 + fmi][fnj], 0, 0, 0);
    __builtin_amdgcn_s_setprio(0);
    __builtin_amdgcn_sched_barrier(0);
    if constexpr (MODE == 0) {
      if (t + 1 < NT) {
        wrA(1, gb);
        if (t + 2 < NT) {
          ldgA(1, t + 2, gb);
          // drain stgB(0,t+1)/stgB(1,t+1); keep the 8 ldgA(t+2) in flight
          asm volatile("s_waitcnt vmcnt(8)" ::: "memory");
        } else {
          asm volatile("s_waitcnt vmcnt(0)" ::: "memory");
        }
      }
    } else {
      if (t + 1 < NT)
        asm volatile("s_waitcnt vmcnt(2)" ::: "memory");
    }
    SBAR();
  }

  // ---- epilogue
  if constexpr (MODE == 0) {
    bf16* PbS = Pb + (size_t)seg * 33554432u;
#pragma unroll
    for (int hk = 0; hk < 2; ++hk) {
      if (wm == hk) {
#pragma unroll
        for (int fn = 0; fn < 4; ++fn) {
          const int col = wn * 64 + fn * 16 + l16;
          const float bv = bias[n0 + col];
#pragma unroll
          for (int fm = 0; fm < 8; ++fm) {
            const int rl0 = fm * 16 + kg * 4;
#pragma unroll
            for (int i = 0; i < 4; ++i) {
              float v = acc[fm][fn][i] + bv;
              if (om == 0) { v *= SCALE_; v = fmaxf(v, 0.f) + EPS_FM_; }
              const int rl = rl0 + i;
              bf16 bvv = (bf16)v;
              *(unsigned short*)(lds + rl * 512 + ((((col >> 3) ^ (rl & 7))) << 4) +
                                 (col & 7) * 2) =
                  __builtin_bit_cast(unsigned short, bvv);
            }
          }
        }
      }
      __syncthreads();
#pragma unroll
      for (int it = 0; it < 8; ++it) {
        const int gi = it * 512 + tid;
        const int row = gi >> 5, g = gi & 31;
        bf16x8 v = *(const bf16x8*)(lds + row * 512 + ((g ^ (row & 7)) << 4));
        *(bf16x8*)(PbS + (size_t)(m0 + hk * 128 + row) * 1024 + n0 + g * 8) = v;
      }
      __syncthreads();
    }
  } else {
#pragma unroll
    for (int fn = 0; fn < 4; ++fn) {
      const int col = n0 + wn * 64 + fn * 16 + l16;
      const float bv = bias[col];
#pragma unroll
      for (int fm = 0; fm < 8; ++fm) {
        const int row = m0 + wm * 128 + fm * 16 + kg * 4;
#pragma unroll
        for (int i = 0; i < 4; ++i)
          Pf[(size_t)(row + i) * 1024 + col] = acc[fm][fn][i] + bv;
      }
    }
  }
}

// ---- KV via MFMA, R11: chunk o+1 global loads issued after the
// post-scatter barrier so they fly under chunk o's MFMA (T14).
__global__ __launch_bounds__(256) void kv_mfma(
    const bf16* __restrict__ Kp, const bf16* __restrict__ Vp,
    float* __restrict__ KVpart, float* __restrict__ KsumPart) {
  __shared__ __align__(16) char lds[65536];
  char* Kt = lds;
  char* Vt = lds + 32768;
  const int bh = blockIdx.x, split = blockIdx.y;
  const int b = bh >> 4, h = bh & 15;
  const int tid = threadIdx.x;
  const int p = tid >> 3, c = tid & 7;
  const int wave = tid >> 6, lane = tid & 63;
  const int wd = wave >> 1, we = wave & 1;
  const int l16 = lane & 15, kg = lane >> 4;
  f32x4 acc[2][2] = {};
  f32x4 accz[2] = {};
  const bf16x8 ones = {1.f, 1.f, 1.f, 1.f, 1.f, 1.f, 1.f, 1.f};
  const size_t gbase0 =
      (size_t)(b * 8192 + split * 1024) * 1024 + h * 64 + c * 8;

  bf16x8 pk0[4], pk1[4], pv0[4], pv1[4];
#pragma unroll
  for (int i = 0; i < 4; ++i) {  // preload chunk 0
    const size_t ga = gbase0 + (size_t)(i * 64 + p * 2) * 1024;
    pk0[i] = *(const bf16x8*)(Kp + ga);
    pk1[i] = *(const bf16x8*)(Kp + ga + 1024);
    pv0[i] = *(const bf16x8*)(Vp + ga);
    pv1[i] = *(const bf16x8*)(Vp + ga + 1024);
  }

  for (int o = 0; o < 4; ++o) {
    __syncthreads();  // waits prev MFMA done AND this chunk's loads (vmcnt)
#pragma unroll
    for (int i = 0; i < 4; ++i) {  // scatter regs -> LDS transposed+swizzled
      const int t = i * 64 + p * 2;
      u16x8 a0 = __builtin_bit_cast(u16x8, pk0[i]);
      u16x8 a1 = __builtin_bit_cast(u16x8, pk1[i]);
      u16x8 b0 = __builtin_bit_cast(u16x8, pv0[i]);
      u16x8 b1 = __builtin_bit_cast(u16x8, pv1[i]);
      const int gt = t >> 3, tl = (t & 7) * 2;
#pragma unroll
      for (int j = 0; j < 8; ++j) {
        const int d = c * 8 + j;
        const int off = d * 512 + ((gt ^ (d & 7) ^ c) << 4) + tl;
        *(unsigned int*)(Kt + off) =
            (unsigned int)a0[j] | ((unsigned int)a1[j] << 16);
        *(unsigned int*)(Vt + off) =
            (unsigned int)b0[j] | ((unsigned int)b1[j] << 16);
      }
    }
    __syncthreads();
    if (o + 1 < 4) {  // issue next chunk's loads; overlap with MFMA below
#pragma unroll
      for (int i = 0; i < 4; ++i) {
        const size_t ga = gbase0 + (size_t)((o + 1) * 256 + i * 64 + p * 2) * 1024;
        pk0[i] = *(const bf16x8*)(Kp + ga);
        pk1[i] = *(const bf16x8*)(Kp + ga + 1024);
        pv0[i] = *(const bf16x8*)(Vp + ga);
        pv1[i] = *(const bf16x8*)(Vp + ga + 1024);
      }
    }

#pragma unroll
    for (int ks = 0; ks < 8; ++ks) {
      const int g = ks * 4 + kg;
      bf16x8 af[2], bf_[2];
#pragma unroll
      for (int f = 0; f < 2; ++f) {
        const int d = wd * 32 + f * 16 + l16;
        af[f] = *(const bf16x8*)(Kt + d * 512 +
                                 ((g ^ (d & 7) ^ ((d >> 3) & 7)) << 4));
        const int ee = we * 32 + f * 16 + l16;
        bf_[f] = *(const bf16x8*)(Vt + ee * 512 +
                                  ((g ^ (ee & 7) ^ ((ee >> 3) & 7)) << 4));
      }
#pragma unroll
      for (int fa = 0; fa < 2; ++fa) {
#pragma unroll
        for (int fb = 0; fb < 2; ++fb)
          acc[fa][fb] = __builtin_amdgcn_mfma_f32_16x16x32_bf16(
              af[fa], bf_[fb], acc[fa][fb], 0, 0, 0);
        if (we == 0)
          accz[fa] = __builtin_amdgcn_mfma_f32_16x16x32_bf16(
              af[fa], ones, accz[fa], 0, 0, 0);
      }
    }
  }

  float* outp = KVpart + ((size_t)split * 64 + bh) * 4096;
#pragma unroll
  for (int fa = 0; fa < 2; ++fa)
#pragma unroll
    for (int i = 0; i < 4; ++i) {
      const int d = wd * 32 + fa * 16 + kg * 4 + i;
#pragma unroll
      for (int fb = 0; fb < 2; ++fb)
        outp[d * 64 + we * 32 + fb * 16 + l16] = acc[fa][fb][i];
      if (we == 0 && l16 == 0)
        KsumPart[((size_t)split * 64 + bh) * 64 + d] = accz[fa][i];
    }
}

// ---- reduce 8 split-partials -> KVt[bh][80][64] bf16; 4 blocks per bh
__global__ __launch_bounds__(256) void kv_reduce(
    const float* __restrict__ KVpart, const float* __restrict__ KsumPart,
    bf16* __restrict__ KVt) {
  int bh = blockIdx.x >> 2;
  int q = blockIdx.x & 3;
  for (int idx = q * 1280 + threadIdx.x; idx < (q + 1) * 1280; idx += 256) {
    float s = 0.f;
    if (idx < 4096) {
      int e = idx >> 6, d = idx & 63;
      for (int sp = 0; sp < 8; ++sp)
        s += KVpart[((size_t)sp * 64 + bh) * 4096 + d * 64 + e];
    } else if (idx < 4160) {
      int d = idx - 4096;
      for (int sp = 0; sp < 8; ++sp)
        s += KsumPart[((size_t)sp * 64 + bh) * 64 + d];
    }
    KVt[(size_t)bh * 5120 + idx] = (bf16)s;
  }
}

// ---- attention (unchanged)
__global__ __launch_bounds__(256) void attn(
    const bf16* __restrict__ KVt, bf16* __restrict__ QA) {
  __shared__ __align__(16) char lds[43008];
  char* Qt = lds;
  char* Bt = lds + 32768;
  const int bh = blockIdx.x, tc = blockIdx.y;
  const int b = bh >> 4, h = bh & 15;
  const int tid = threadIdx.x;
  const int m0 = b * 8192 + tc * 256;

#pragma unroll
  for (int i = 0; i < 8; ++i) {
    const int gidx = i * 256 + tid;
    const int row = gidx >> 3, g = gidx & 7;
    const int gsrc = g ^ (row & 7);
    gl_lds16(QA + (size_t)(m0 + row) * 1024 + h * 64 + gsrc * 8, Qt + gidx * 16);
  }
#pragma unroll
  for (int i = 0; i < 3; ++i) {
    const int gidx = i * 256 + tid;
    if (gidx < 640) {
      const int row = gidx >> 3, g = gidx & 7;
      const int gsrc = g ^ (row & 7);
      gl_lds16(KVt + (size_t)bh * 5120 + row * 64 + gsrc * 8, Bt + gidx * 16);
    }
  }
  __syncthreads();

  const int wave = tid >> 6, lane = tid & 63;
  const int l16 = lane & 15, kg = lane >> 4;
  bf16x8 a[4][2];
#pragma unroll
  for (int fm = 0; fm < 4; ++fm)
#pragma unroll
    for (int kk = 0; kk < 2; ++kk) {
      const int row = wave * 64 + fm * 16 + l16;
      const int g = kk * 4 + kg;
      a[fm][kk] = *(const bf16x8*)(Qt + row * 128 + ((g ^ (row & 7)) << 4));
    }
  f32x4 acc[4][4] = {};
  f32x4 accz[4] = {};
#pragma unroll
  for (int kk = 0; kk < 2; ++kk) {
    const int g = kk * 4 + kg;
    const int zr = 64 + l16;
    bf16x8 bz = *(const bf16x8*)(Bt + zr * 128 + ((g ^ (zr & 7)) << 4));
#pragma unroll
    for (int fn = 0; fn < 4; ++fn) {
      const int br = fn * 16 + l16;
      bf16x8 bb = *(const bf16x8*)(Bt + br * 128 + ((g ^ (br & 7)) << 4));
#pragma unroll
      for (int fm = 0; fm < 4; ++fm)
        acc[fm][fn] = __builtin_amdgcn_mfma_f32_16x16x32_bf16(
            a[fm][kk], bb, acc[fm][fn], 0, 0, 0);
    }
#pragma unroll
    for (int fm = 0; fm < 4; ++fm)
      accz[fm] = __builtin_amdgcn_mfma_f32_16x16x32_bf16(
          a[fm][kk], bz, accz[fm], 0, 0, 0);
  }
  __syncthreads();

#pragma unroll
  for (int fm = 0; fm < 4; ++fm)
#pragma unroll
    for (int i = 0; i < 4; ++i) {
      const float z = __shfl(accz[fm][i], (lane & 48), 64) + EPS_Z_;
      const float rz = 1.0f / z;
      const int row = wave * 64 + fm * 16 + kg * 4 + i;
#pragma unroll
      for (int fn = 0; fn < 4; ++fn) {
        const int col = fn * 16 + l16;
        const int gc = col >> 3;
        bf16 v = (bf16)(acc[fm][fn][i] * rz);
        *(unsigned short*)(Qt + row * 128 + ((gc ^ (row & 7)) << 4) + (col & 7) * 2) =
            __builtin_bit_cast(unsigned short, v);
      }
    }
  __syncthreads();

#pragma unroll
  for (int i = 0; i < 8; ++i) {
    const int gidx = i * 256 + tid;
    const int row = gidx >> 3, g = gidx & 7;
    bf16x8 v = *(const bf16x8*)(Qt + row * 128 + ((g ^ (row & 7)) << 4));
    *(bf16x8*)(QA + (size_t)(m0 + row) * 1024 + h * 64 + g * 8) = v;
  }
}

extern "C" void kernel_launch(void* const* d_in, const int* in_sizes, int n_in,
                              void* d_out, int out_size, void* d_ws, size_t ws_size,
                              hipStream_t stream) {
  const float* query = (const float*)d_in[0];
  const float* key = (const float*)d_in[1];
  const float* value = (const float*)d_in[2];
  const float* Wq = (const float*)d_in[3];
  const float* bq = (const float*)d_in[4];
  const float* Wk = (const float*)d_in[5];
  const float* bk = (const float*)d_in[6];
  const float* Wv = (const float*)d_in[7];
  const float* bv = (const float*)d_in[8];
  const float* Wo = (const float*)d_in[9];
  const float* bo = (const float*)d_in[10];
  float* out = (float*)d_out;

  bf16* ws = (bf16*)d_ws;
  bf16* Wqb = ws;
  bf16* Wob = ws + (3u << 20);
  bf16* Qp = ws + (4u << 20);
  bf16* Kp = Qp + 33554432u;
  bf16* Vp = Kp + 33554432u;
  bf16* KVt = Vp + 33554432u;
  float* KVpart = (float*)d_out + 16777216u;      // 8 x 64 x 4096 fp32 = 8MB
  float* KsumPart = KVpart + 8 * 64 * 4096;       // 8 x 64 x 64 fp32

  cast_weights<<<dim3(1024, 4), 256, 0, stream>>>(Wq, Wk, Wv, Wo, Wqb);

  gemm8p<0><<<1536, 512, 0, stream>>>(nullptr, query, key, value, Wqb, bq, bk,
                                      bv, Qp, nullptr);

  kv_mfma<<<dim3(64, 8), 256, 0, stream>>>(Kp, Vp, KVpart, KsumPart);
  kv_reduce<<<256, 256, 0, stream>>>(KVpart, KsumPart, KVt);
  attn<<<dim3(64, 32), 256, 0, stream>>>(KVt, Qp);
  gemm8p<1><<<512, 512, 0, stream>>>(Qp, nullptr, nullptr, nullptr, Wob, bo,
                                     bo, bo, nullptr, out);
}